// Round 1
// baseline (395.746 us; speedup 1.0000x reference)
//
#include <hip/hip_runtime.h>

#define BATCH 4
#define NN 512
#define HID 256
#define EDIM 16
#define HEADS 8
#define HDIM 32

// ---------- kernel 0: pack edge-MLP weights per hidden unit ----------
// pack[u][0..15] = We1[e][u], pack[u][16] = be1[u], pack[u][17..24] = We2[u][h]
__global__ void k_pack(const float* __restrict__ We1, const float* __restrict__ be1,
                       const float* __restrict__ We2, float* __restrict__ pack) {
    int u = threadIdx.x;  // 256 threads
    float* p = pack + u * 32;
#pragma unroll
    for (int e = 0; e < EDIM; ++e) p[e] = We1[e * HID + u];
    p[16] = be1[u];
#pragma unroll
    for (int h = 0; h < HEADS; ++h) p[17 + h] = We2[u * HEADS + h];
}

// ---------- kernel 1: QKV projections ----------
__global__ __launch_bounds__(256) void k_qkv(
    const float* __restrict__ node_h,
    const float* __restrict__ Wq, const float* __restrict__ bq,
    const float* __restrict__ Wk, const float* __restrict__ bk,
    const float* __restrict__ Wv, const float* __restrict__ bv,
    float* __restrict__ q, float* __restrict__ k, float* __restrict__ v) {
    int bi = blockIdx.x;          // b*NN + i
    int b = bi >> 9, i = bi & (NN - 1);
    int t = threadIdx.x;
    __shared__ float s_h[HID];
    s_h[t] = node_h[(size_t)bi * HID + t];
    __syncthreads();
    float aq = bq[t], ak = bk[t], av = bv[t];
#pragma unroll 8
    for (int r = 0; r < HID; ++r) {
        float x = s_h[r];
        aq = fmaf(x, Wq[r * HID + t], aq);
        ak = fmaf(x, Wk[r * HID + t], ak);
        av = fmaf(x, Wv[r * HID + t], av);
    }
    int h = t >> 5, d = t & 31;
    size_t idx = ((size_t)(b * HEADS + h) * NN + i) * HDIM + d;
    q[idx] = aq; k[idx] = ak; v[idx] = av;
}

// ---------- kernel 2: fused scores + edge MLP + softmax + attn@V ----------
__global__ __launch_bounds__(256) void k_attn(
    const float* __restrict__ edge_x, const int* __restrict__ emask,
    const float* __restrict__ q, const float* __restrict__ k, const float* __restrict__ v,
    const float* __restrict__ pack, const float* __restrict__ be2,
    float* __restrict__ attn, float* __restrict__ ao) {
    int bi = blockIdx.x;          // b*NN + i
    int b = bi >> 9, i = bi & (NN - 1);
    int t = threadIdx.x;

    __shared__ float s_sc[HEADS][NN];       // 16 KB: scores then attn
    __shared__ float s_ex[NN][EDIM + 1];    // 34816 B, +1 pad kills bank conflicts
    __shared__ float s_q[HID];              // 1 KB

    // load q row for this (b,i): q[b,h,i,:]
    {
        int h = t >> 5, d = t & 31;
        s_q[t] = q[((size_t)(b * HEADS + h) * NN + i) * HDIM + d];
    }
    // stage edge_x[b][i][:][:] (8192 contiguous floats) into LDS
    {
        const float4* src = (const float4*)(edge_x + (size_t)bi * NN * EDIM);
        for (int idx4 = t; idx4 < NN * EDIM / 4; idx4 += 256) {
            float4 w = src[idx4];
            int fl = idx4 * 4;
            int j = fl >> 4, e = fl & 15;
            s_ex[j][e + 0] = w.x; s_ex[j][e + 1] = w.y;
            s_ex[j][e + 2] = w.z; s_ex[j][e + 3] = w.w;
        }
    }
    __syncthreads();

    // QK^T scores with leaky relu; each rep handles one uniform h, 256 j's
    const float scale = 0.17677669529663687f;  // 1/sqrt(32)
#pragma unroll
    for (int rep = 0; rep < 16; ++rep) {
        int idx = rep * 256 + t;
        int h = idx >> 9, j = idx & (NN - 1);
        const float4* kr = (const float4*)(k + ((size_t)(b * HEADS + h) * NN + j) * HDIM);
        float acc = 0.f;
#pragma unroll
        for (int d4 = 0; d4 < 8; ++d4) {
            float4 kv = kr[d4];
            acc = fmaf(s_q[h * HDIM + d4 * 4 + 0], kv.x, acc);
            acc = fmaf(s_q[h * HDIM + d4 * 4 + 1], kv.y, acc);
            acc = fmaf(s_q[h * HDIM + d4 * 4 + 2], kv.z, acc);
            acc = fmaf(s_q[h * HDIM + d4 * 4 + 3], kv.w, acc);
        }
        acc *= scale;
        acc = acc > 0.f ? acc : 0.2f * acc;   // leaky_relu slope 0.2
        s_sc[h][j] = acc;
    }
    __syncthreads();

    // edge MLP: lane owns j0=t, j1=t+256; weights at uniform addresses (SGPR path)
    {
        float ex0[EDIM], ex1[EDIM];
#pragma unroll
        for (int e = 0; e < EDIM; ++e) { ex0[e] = s_ex[t][e]; ex1[e] = s_ex[t + 256][e]; }
        float acc0[HEADS], acc1[HEADS];
#pragma unroll
        for (int h = 0; h < HEADS; ++h) { float bb = be2[h]; acc0[h] = bb; acc1[h] = bb; }
        for (int u = 0; u < HID; ++u) {
            const float* p = pack + u * 32;
            float h0 = p[16], h1 = p[16];
#pragma unroll
            for (int e = 0; e < EDIM; ++e) {
                float w = p[e];
                h0 = fmaf(ex0[e], w, h0);
                h1 = fmaf(ex1[e], w, h1);
            }
            h0 = fmaxf(h0, 0.f); h1 = fmaxf(h1, 0.f);
#pragma unroll
            for (int h = 0; h < HEADS; ++h) {
                float w = p[17 + h];
                acc0[h] = fmaf(h0, w, acc0[h]);
                acc1[h] = fmaf(h1, w, acc1[h]);
            }
        }
#pragma unroll
        for (int h = 0; h < HEADS; ++h) {
            s_sc[h][t]       += acc0[h];   // lane exclusively owns columns t, t+256
            s_sc[h][t + 256] += acc1[h];
        }
    }
    __syncthreads();

    // mask + softmax per (h) row; wave w handles h=w and h=w+4
    int wave = t >> 6, lane = t & 63;
#pragma unroll
    for (int hh = 0; hh < 2; ++hh) {
        int h = wave + hh * 4;
        float vals[8];
        float mx = -1e30f;
#pragma unroll
        for (int l = 0; l < 8; ++l) {
            int j = lane + l * 64;
            float s = s_sc[h][j];
            bool valid = (emask[(size_t)bi * NN + j] != 0) || (j == i);
            s = valid ? s : -1e9f;
            vals[l] = s;
            mx = fmaxf(mx, s);
        }
#pragma unroll
        for (int off = 32; off > 0; off >>= 1) mx = fmaxf(mx, __shfl_xor(mx, off));
        float sum = 0.f;
#pragma unroll
        for (int l = 0; l < 8; ++l) { vals[l] = __expf(vals[l] - mx); sum += vals[l]; }
#pragma unroll
        for (int off = 32; off > 0; off >>= 1) sum += __shfl_xor(sum, off);
        float inv = 1.f / sum;
        float* arow = attn + ((size_t)(b * HEADS + h) * NN + i) * NN;
#pragma unroll
        for (int l = 0; l < 8; ++l) {
            int j = lane + l * 64;
            float a = vals[l] * inv;
            s_sc[h][j] = a;
            arow[j] = a;
        }
    }
    __syncthreads();

    // attn @ V : thread t owns (h,d)
    {
        int h = t >> 5, d = t & 31;
        const float* vb = v + (size_t)(b * HEADS + h) * NN * HDIM + d;
        float acc = 0.f;
#pragma unroll 8
        for (int j = 0; j < NN; ++j)
            acc = fmaf(s_sc[h][j], vb[(size_t)j * HDIM], acc);
        ao[(size_t)bi * HID + t] = acc;   // layout already h*32+d = output channel
    }
}

// ---------- kernel 3: Wo + residual + LayerNorm + relu ----------
__global__ __launch_bounds__(256) void k_final(
    const float* __restrict__ ao, const float* __restrict__ node_h,
    const float* __restrict__ Wo, const float* __restrict__ bo,
    const float* __restrict__ ln_g, const float* __restrict__ ln_b,
    float* __restrict__ out) {
    int bi = blockIdx.x;
    int t = threadIdx.x;
    __shared__ float s_a[HID];
    __shared__ float s_s1[4], s_s2[4];
    s_a[t] = ao[(size_t)bi * HID + t];
    __syncthreads();
    float o = bo[t];
#pragma unroll 8
    for (int r = 0; r < HID; ++r) o = fmaf(s_a[r], Wo[r * HID + t], o);
    float x = node_h[(size_t)bi * HID + t] + o;
    float s1 = x, s2 = x * x;
#pragma unroll
    for (int off = 32; off > 0; off >>= 1) { s1 += __shfl_xor(s1, off); s2 += __shfl_xor(s2, off); }
    int wave = t >> 6, lane = t & 63;
    if (lane == 0) { s_s1[wave] = s1; s_s2[wave] = s2; }
    __syncthreads();
    s1 = s_s1[0] + s_s1[1] + s_s1[2] + s_s1[3];
    s2 = s_s2[0] + s_s2[1] + s_s2[2] + s_s2[3];
    float mean = s1 * (1.f / HID);
    float var = s2 * (1.f / HID) - mean * mean;
    float inv = rsqrtf(var + 1e-5f);
    float y = (x - mean) * inv * ln_g[t] + ln_b[t];
    out[(size_t)bi * HID + t] = fmaxf(y, 0.f);
}

extern "C" void kernel_launch(void* const* d_in, const int* in_sizes, int n_in,
                              void* d_out, int out_size, void* d_ws, size_t ws_size,
                              hipStream_t stream) {
    const float* node_h = (const float*)d_in[0];
    const float* edge_x = (const float*)d_in[1];
    const int*   emask  = (const int*)d_in[2];
    const float* Wq = (const float*)d_in[3];
    const float* bq = (const float*)d_in[4];
    const float* Wk = (const float*)d_in[5];
    const float* bk = (const float*)d_in[6];
    const float* Wv = (const float*)d_in[7];
    const float* bv = (const float*)d_in[8];
    const float* We1 = (const float*)d_in[9];
    const float* be1 = (const float*)d_in[10];
    const float* We2 = (const float*)d_in[11];
    const float* be2 = (const float*)d_in[12];
    const float* Wo = (const float*)d_in[13];
    const float* bo = (const float*)d_in[14];
    const float* ln_g = (const float*)d_in[15];
    const float* ln_b = (const float*)d_in[16];

    float* out_x  = (float*)d_out;                              // [4,512,256]
    float* out_at = (float*)d_out + (size_t)BATCH * NN * HID;   // [4,8,512,512]

    float* ws = (float*)d_ws;
    float* q    = ws;                                  // 524288
    float* kbuf = ws + 524288;                         // 524288
    float* vbuf = ws + 1048576;                        // 524288
    float* ao   = ws + 1572864;                        // 524288
    float* pack = ws + 2097152;                        // 8192

    const int NBI = BATCH * NN;  // 2048

    hipLaunchKernelGGL(k_pack, dim3(1), dim3(256), 0, stream, We1, be1, We2, pack);
    hipLaunchKernelGGL(k_qkv, dim3(NBI), dim3(256), 0, stream,
                       node_h, Wq, bq, Wk, bk, Wv, bv, q, kbuf, vbuf);
    hipLaunchKernelGGL(k_attn, dim3(NBI), dim3(256), 0, stream,
                       edge_x, emask, q, kbuf, vbuf, pack, be2, out_at, ao);
    hipLaunchKernelGGL(k_final, dim3(NBI), dim3(256), 0, stream,
                       ao, node_h, Wo, bo, ln_g, ln_b, out_x);
}

// Round 2
// 226.980 us; speedup vs baseline: 1.7435x; 1.7435x over previous
//
#include <hip/hip_runtime.h>

#define BATCH 4
#define NN 512
#define HID 256
#define EDIM 16
#define HEADS 8
#define HDIM 32

typedef __attribute__((ext_vector_type(8))) short bf16x8;
typedef __attribute__((ext_vector_type(4))) float f32x4;

__device__ inline unsigned short bf16_hi(float x) {
    return (unsigned short)(__float_as_uint(x) >> 16);
}
__device__ inline float bf16_f(unsigned short s) {
    return __uint_as_float(((unsigned)s) << 16);
}

// ---------- kernel 0: pack W1 into MFMA A-fragment order ----------
// A-frag (M=units 16, K=32 slots = [W1hi(e=0..15); W1lo(e=0..15)]):
// lane l=16q+r holds slots q*8+j  ->  e=(q&1)*8+j, part = q>>1 (0=hi,1=lo),
// value源 We1[e][ut*16+r].  W1P[ut][lane][j] ushort, 16 KB.
__global__ void k_pack(const float* __restrict__ We1, unsigned short* __restrict__ W1P) {
    int t = threadIdx.x;  // 256 threads
#pragma unroll
    for (int rep = 0; rep < 4; ++rep) {
        int p = rep * 256 + t;          // (ut, lane) pair, 1024 total
        int ut = p >> 6, lane = p & 63;
        int q = lane >> 4, r = lane & 15;
#pragma unroll
        for (int j = 0; j < 8; ++j) {
            int e = (q & 1) * 8 + j;
            float val = We1[e * HID + ut * 16 + r];
            unsigned short hi = bf16_hi(val);
            unsigned short outv;
            if (q < 2) outv = hi;
            else {
                float rem = val - bf16_f(hi);
                outv = bf16_hi(rem);
            }
            W1P[p * 8 + j] = outv;
        }
    }
}

// ---------- kernel 1: QKV projections (unchanged) ----------
__global__ __launch_bounds__(256) void k_qkv(
    const float* __restrict__ node_h,
    const float* __restrict__ Wq, const float* __restrict__ bq,
    const float* __restrict__ Wk, const float* __restrict__ bk,
    const float* __restrict__ Wv, const float* __restrict__ bv,
    float* __restrict__ q, float* __restrict__ k, float* __restrict__ v) {
    int bi = blockIdx.x;
    int b = bi >> 9, i = bi & (NN - 1);
    int t = threadIdx.x;
    __shared__ float s_h[HID];
    s_h[t] = node_h[(size_t)bi * HID + t];
    __syncthreads();
    float aq = bq[t], ak = bk[t], av = bv[t];
#pragma unroll 8
    for (int r = 0; r < HID; ++r) {
        float x = s_h[r];
        aq = fmaf(x, Wq[r * HID + t], aq);
        ak = fmaf(x, Wk[r * HID + t], ak);
        av = fmaf(x, Wv[r * HID + t], av);
    }
    int h = t >> 5, d = t & 31;
    size_t idx = ((size_t)(b * HEADS + h) * NN + i) * HDIM + d;
    q[idx] = aq; k[idx] = ak; v[idx] = av;
}

// ---------- kernel 2: fused eb-MFMA + scores + softmax + attn@V ----------
// One block = (b, i0..i0+3).  512 blocks, 256 threads (4 waves).
__global__ __launch_bounds__(256, 2) void k_attn(
    const float* __restrict__ edge_x, const int* __restrict__ emask,
    const float* __restrict__ q, const float* __restrict__ k, const float* __restrict__ v,
    const unsigned short* __restrict__ W1P,
    const float* __restrict__ be1, const float* __restrict__ We2, const float* __restrict__ be2,
    float* __restrict__ attn, float* __restrict__ ao) {
    int bid = blockIdx.x;
    int b = bid >> 7, i0 = (bid & 127) << 2;
    int t = threadIdx.x;
    int w = t >> 6, lane = t & 63;
    int qq = lane >> 4, r = lane & 15;

    __shared__ float s_sc[HEADS][NN][4];   // 64 KB  [h][j][qi]
    __shared__ float s_q[4][HID];          // 4 KB
    __shared__ int   s_m[4][NN];           // 8 KB

    // ---- P0: stage q rows + mask rows ----
#pragma unroll
    for (int u = 0; u < 4; ++u) {
        int h = t >> 5, d = t & 31;
        s_q[u][t] = q[((size_t)(b * HEADS + h) * NN + (i0 + u)) * HDIM + d];
    }
#pragma unroll
    for (int u = 0; u < 8; ++u) {
        int idx = u * 256 + t;
        int qi = idx >> 9, j = idx & (NN - 1);
        s_m[qi][j] = emask[((size_t)b * NN + i0 + qi) * NN + j];
    }

    // ---- P1: edge-bias MLP via MFMA (layer1) + per-lane fp32 (layer2) ----
    // wave w owns local rows lr = w*512 .. w*512+511  (qi = w, j = lr&511)
    {
        size_t brb = ((size_t)b * NN + i0) * NN;   // block edge-row base
        float2 be2v = *(const float2*)(be2 + qq * 2);
        for (int c = 0; c < 8; ++c) {
            int lr0 = w * 512 + c * 64;
            bf16x8 bhi[4], blo[4];
#pragma unroll
            for (int rt = 0; rt < 4; ++rt) {
                size_t g = brb + lr0 + rt * 16 + r;
                const float4* p = (const float4*)(edge_x + g * EDIM + (qq & 1) * 8);
                float4 x0 = p[0], x1 = p[1];
                float xs[8] = {x0.x, x0.y, x0.z, x0.w, x1.x, x1.y, x1.z, x1.w};
#pragma unroll
                for (int j = 0; j < 8; ++j) {
                    unsigned short h16 = bf16_hi(xs[j]);
                    float rem = xs[j] - bf16_f(h16);
                    bhi[rt][j] = (short)h16;
                    blo[rt][j] = (short)bf16_hi(rem);
                }
            }
            float pacc[4][8];
#pragma unroll
            for (int rt = 0; rt < 4; ++rt)
#pragma unroll
                for (int hd = 0; hd < 8; ++hd) pacc[rt][hd] = 0.f;

            for (int ut = 0; ut < 16; ++ut) {
                bf16x8 afrag = *(const bf16x8*)(W1P + ((size_t)ut * 64 + lane) * 8);
                f32x4 be1v = *(const f32x4*)(be1 + ut * 16 + qq * 4);
                float w2[4][8];
#pragma unroll
                for (int reg = 0; reg < 4; ++reg) {
                    const float4* wp = (const float4*)(We2 + (ut * 16 + qq * 4 + reg) * HEADS);
                    float4 wa = wp[0], wb = wp[1];
                    w2[reg][0] = wa.x; w2[reg][1] = wa.y; w2[reg][2] = wa.z; w2[reg][3] = wa.w;
                    w2[reg][4] = wb.x; w2[reg][5] = wb.y; w2[reg][6] = wb.z; w2[reg][7] = wb.w;
                }
#pragma unroll
                for (int rt = 0; rt < 4; ++rt) {
                    f32x4 cfr = __builtin_amdgcn_mfma_f32_16x16x32_bf16(afrag, bhi[rt], be1v, 0, 0, 0);
                    cfr = __builtin_amdgcn_mfma_f32_16x16x32_bf16(afrag, blo[rt], cfr, 0, 0, 0);
#pragma unroll
                    for (int reg = 0; reg < 4; ++reg) {
                        float hv = fmaxf(cfr[reg], 0.f);
#pragma unroll
                        for (int hd = 0; hd < 8; ++hd)
                            pacc[rt][hd] = fmaf(hv, w2[reg][hd], pacc[rt][hd]);
                    }
                }
            }
            // reduce partial sums across the 4 q-groups (units split)
#pragma unroll
            for (int rt = 0; rt < 4; ++rt)
#pragma unroll
                for (int hd = 0; hd < 8; ++hd) {
                    float vv = pacc[rt][hd];
                    vv += __shfl_xor(vv, 16);
                    vv += __shfl_xor(vv, 32);
                    pacc[rt][hd] = vv;
                }
            // each lane writes heads qq*2, qq*2+1 (static pacc indices)
#pragma unroll
            for (int rt = 0; rt < 4; ++rt) {
                int j = c * 64 + rt * 16 + r;
                float v0 = (qq == 0) ? pacc[rt][0] : (qq == 1) ? pacc[rt][2] : (qq == 2) ? pacc[rt][4] : pacc[rt][6];
                float v1 = (qq == 0) ? pacc[rt][1] : (qq == 1) ? pacc[rt][3] : (qq == 2) ? pacc[rt][5] : pacc[rt][7];
                s_sc[qq * 2 + 0][j][w] = v0 + be2v.x;
                s_sc[qq * 2 + 1][j][w] = v1 + be2v.y;
            }
        }
    }
    __syncthreads();

    // ---- P2: QK^T + leaky relu + eb + mask ----
    const float scale = 0.17677669529663687f;  // 1/sqrt(32)
#pragma unroll
    for (int rep = 0; rep < 16; ++rep) {
        int idx = rep * 256 + t;
        int h = idx >> 9, j = idx & (NN - 1);
        const float4* kr = (const float4*)(k + (((size_t)b * HEADS + h) * NN + j) * HDIM);
        float4 kk[8];
#pragma unroll
        for (int d4 = 0; d4 < 8; ++d4) kk[d4] = kr[d4];
        float4 sv = *(float4*)(&s_sc[h][j][0]);
        float accq[4];
#pragma unroll
        for (int qi = 0; qi < 4; ++qi) {
            const float4* qp = (const float4*)(&s_q[qi][h * HDIM]);
            float a = 0.f;
#pragma unroll
            for (int d4 = 0; d4 < 8; ++d4) {
                float4 qv = qp[d4];
                a = fmaf(qv.x, kk[d4].x, a);
                a = fmaf(qv.y, kk[d4].y, a);
                a = fmaf(qv.z, kk[d4].z, a);
                a = fmaf(qv.w, kk[d4].w, a);
            }
            accq[qi] = a;
        }
        float4 so;
#pragma unroll
        for (int qi = 0; qi < 4; ++qi) {
            float s = accq[qi] * scale;
            s = s > 0.f ? s : 0.2f * s;
            s += (qi == 0) ? sv.x : (qi == 1) ? sv.y : (qi == 2) ? sv.z : sv.w;
            bool valid = (s_m[qi][j] != 0) || (j == i0 + qi);
            float res = valid ? s : -1e9f;
            if (qi == 0) so.x = res; else if (qi == 1) so.y = res; else if (qi == 2) so.z = res; else so.w = res;
        }
        *(float4*)(&s_sc[h][j][0]) = so;
    }
    __syncthreads();

    // ---- P3: softmax per (qi=w, h) row + write attn ----
    {
        int qi = w;
#pragma unroll
        for (int h = 0; h < HEADS; ++h) {
            float vals[8];
            float mx = -3e38f;
#pragma unroll
            for (int l = 0; l < 8; ++l) {
                vals[l] = s_sc[h][lane + l * 64][qi];
                mx = fmaxf(mx, vals[l]);
            }
#pragma unroll
            for (int off = 32; off > 0; off >>= 1) mx = fmaxf(mx, __shfl_xor(mx, off));
            float sum = 0.f;
#pragma unroll
            for (int l = 0; l < 8; ++l) { vals[l] = __expf(vals[l] - mx); sum += vals[l]; }
#pragma unroll
            for (int off = 32; off > 0; off >>= 1) sum += __shfl_xor(sum, off);
            float inv = 1.f / sum;
            float* arow = attn + (((size_t)b * HEADS + h) * NN + (i0 + qi)) * NN;
#pragma unroll
            for (int l = 0; l < 8; ++l) {
                float a = vals[l] * inv;
                arow[lane + l * 64] = a;
                s_sc[h][lane + l * 64][qi] = a;
            }
        }
    }
    __syncthreads();

    // ---- P4: attn @ V ----
    {
        int h = t >> 5, d = t & 31;
        const float* vp = v + (((size_t)b * HEADS + h) * NN) * HDIM + d;
        float a0 = 0.f, a1 = 0.f, a2 = 0.f, a3 = 0.f;
#pragma unroll 8
        for (int j = 0; j < NN; ++j) {
            float vv = vp[(size_t)j * HDIM];
            float4 aw = *(float4*)(&s_sc[h][j][0]);
            a0 = fmaf(aw.x, vv, a0);
            a1 = fmaf(aw.y, vv, a1);
            a2 = fmaf(aw.z, vv, a2);
            a3 = fmaf(aw.w, vv, a3);
        }
        ao[((size_t)b * NN + i0 + 0) * HID + t] = a0;
        ao[((size_t)b * NN + i0 + 1) * HID + t] = a1;
        ao[((size_t)b * NN + i0 + 2) * HID + t] = a2;
        ao[((size_t)b * NN + i0 + 3) * HID + t] = a3;
    }
}

// ---------- kernel 3: Wo + residual + LayerNorm + relu (unchanged) ----------
__global__ __launch_bounds__(256) void k_final(
    const float* __restrict__ ao, const float* __restrict__ node_h,
    const float* __restrict__ Wo, const float* __restrict__ bo,
    const float* __restrict__ ln_g, const float* __restrict__ ln_b,
    float* __restrict__ out) {
    int bi = blockIdx.x;
    int t = threadIdx.x;
    __shared__ float s_a[HID];
    __shared__ float s_s1[4], s_s2[4];
    s_a[t] = ao[(size_t)bi * HID + t];
    __syncthreads();
    float o = bo[t];
#pragma unroll 8
    for (int r = 0; r < HID; ++r) o = fmaf(s_a[r], Wo[r * HID + t], o);
    float x = node_h[(size_t)bi * HID + t] + o;
    float s1 = x, s2 = x * x;
#pragma unroll
    for (int off = 32; off > 0; off >>= 1) { s1 += __shfl_xor(s1, off); s2 += __shfl_xor(s2, off); }
    int wave = t >> 6, lane = t & 63;
    if (lane == 0) { s_s1[wave] = s1; s_s2[wave] = s2; }
    __syncthreads();
    s1 = s_s1[0] + s_s1[1] + s_s1[2] + s_s1[3];
    s2 = s_s2[0] + s_s2[1] + s_s2[2] + s_s2[3];
    float mean = s1 * (1.f / HID);
    float var = s2 * (1.f / HID) - mean * mean;
    float inv = rsqrtf(var + 1e-5f);
    float y = (x - mean) * inv * ln_g[t] + ln_b[t];
    out[(size_t)bi * HID + t] = fmaxf(y, 0.f);
}

extern "C" void kernel_launch(void* const* d_in, const int* in_sizes, int n_in,
                              void* d_out, int out_size, void* d_ws, size_t ws_size,
                              hipStream_t stream) {
    const float* node_h = (const float*)d_in[0];
    const float* edge_x = (const float*)d_in[1];
    const int*   emask  = (const int*)d_in[2];
    const float* Wq = (const float*)d_in[3];
    const float* bq = (const float*)d_in[4];
    const float* Wk = (const float*)d_in[5];
    const float* bk = (const float*)d_in[6];
    const float* Wv = (const float*)d_in[7];
    const float* bv = (const float*)d_in[8];
    const float* We1 = (const float*)d_in[9];
    const float* be1 = (const float*)d_in[10];
    const float* We2 = (const float*)d_in[11];
    const float* be2 = (const float*)d_in[12];
    const float* Wo = (const float*)d_in[13];
    const float* bo = (const float*)d_in[14];
    const float* ln_g = (const float*)d_in[15];
    const float* ln_b = (const float*)d_in[16];

    float* out_x  = (float*)d_out;                              // [4,512,256]
    float* out_at = (float*)d_out + (size_t)BATCH * NN * HID;   // [4,8,512,512]

    float* ws = (float*)d_ws;
    float* q    = ws;                                  // 524288 floats
    float* kbuf = ws + 524288;
    float* vbuf = ws + 1048576;
    float* ao   = ws + 1572864;
    unsigned short* W1P = (unsigned short*)(ws + 2097152);  // 8192 ushorts

    const int NBI = BATCH * NN;  // 2048

    hipLaunchKernelGGL(k_pack, dim3(1), dim3(256), 0, stream, We1, W1P);
    hipLaunchKernelGGL(k_qkv, dim3(NBI), dim3(256), 0, stream,
                       node_h, Wq, bq, Wk, bk, Wv, bv, q, kbuf, vbuf);
    hipLaunchKernelGGL(k_attn, dim3(NBI / 4), dim3(256), 0, stream,
                       edge_x, emask, q, kbuf, vbuf, W1P, be1, We2, be2, out_at, ao);
    hipLaunchKernelGGL(k_final, dim3(NBI), dim3(256), 0, stream,
                       ao, node_h, Wo, bo, ln_g, ln_b, out_x);
}

// Round 3
// 187.855 us; speedup vs baseline: 2.1067x; 1.2083x over previous
//
#include <hip/hip_runtime.h>

#define BATCH 4
#define NN 512
#define HID 256
#define EDIM 16
#define HEADS 8
#define HDIM 32

typedef __attribute__((ext_vector_type(8))) short bf16x8;
typedef __attribute__((ext_vector_type(4))) float f32x4;

__device__ inline unsigned short bf16_hi(float x) {
    return (unsigned short)(__float_as_uint(x) >> 16);
}
__device__ inline float bf16_f(unsigned short s) {
    return __uint_as_float(((unsigned)s) << 16);
}
__device__ inline unsigned short bf16_rn(float x) {
    unsigned u = __float_as_uint(x);
    unsigned r = u + 0x7FFFu + ((u >> 16) & 1u);
    return (unsigned short)(r >> 16);
}

// ---------- kernel 0: pack W1 (hi/lo A-frags) + W2 (bf16 B-frags, N=16 pad) ----------
// W1P: lane l=16q+r of tile ut holds A[row r=unit][slot q*8+j]; slots 0-15 = W1hi(e),
//      slots 16-31 = W1lo(e).  1024*8 ushorts.
// W2P: lane l=16q+r of tile kt holds B[slot q*8+jj -> unit kt*32+q*8+jj][col r=head],
//      cols 8..15 zero.  512*8 ushorts.
__global__ void k_pack(const float* __restrict__ We1, const float* __restrict__ We2,
                       unsigned short* __restrict__ W1P, unsigned short* __restrict__ W2P) {
    int t = threadIdx.x;  // 256 threads
#pragma unroll
    for (int rep = 0; rep < 4; ++rep) {
        int p = rep * 256 + t;          // (ut, lane)
        int ut = p >> 6, lane = p & 63;
        int q = lane >> 4, r = lane & 15;
#pragma unroll
        for (int j = 0; j < 8; ++j) {
            int e = (q & 1) * 8 + j;
            float val = We1[e * HID + ut * 16 + r];
            unsigned short hi = bf16_hi(val);
            unsigned short outv;
            if (q < 2) outv = hi;
            else outv = bf16_hi(val - bf16_f(hi));
            W1P[p * 8 + j] = outv;
        }
    }
#pragma unroll
    for (int rep = 0; rep < 2; ++rep) {
        int p = rep * 256 + t;          // (kt, lane)
        int kt = p >> 6, lane = p & 63;
        int q = lane >> 4, r = lane & 15;
#pragma unroll
        for (int jj = 0; jj < 8; ++jj) {
            int unit = kt * 32 + q * 8 + jj;
            float val = (r < 8) ? We2[unit * HEADS + r] : 0.f;
            W2P[p * 8 + jj] = bf16_rn(val);
        }
    }
}

// ---------- kernel 1: QKV projections, 8 rows/block ----------
__global__ __launch_bounds__(256) void k_qkv(
    const float* __restrict__ node_h,
    const float* __restrict__ Wq, const float* __restrict__ bq,
    const float* __restrict__ Wk, const float* __restrict__ bk,
    const float* __restrict__ Wv, const float* __restrict__ bv,
    float* __restrict__ q, float* __restrict__ k, float* __restrict__ v) {
    int blk = blockIdx.x;           // 256 blocks
    int b = blk >> 6, i0 = (blk & 63) << 3;
    int t = threadIdx.x;
    __shared__ __align__(16) float s_h[8][HID];
#pragma unroll
    for (int u = 0; u < 8; ++u)
        s_h[u][t] = node_h[((size_t)b * NN + i0 + u) * HID + t];
    __syncthreads();
    float aq[8], ak[8], av[8];
    float bqv = bq[t], bkv = bk[t], bvv = bv[t];
#pragma unroll
    for (int u = 0; u < 8; ++u) { aq[u] = bqv; ak[u] = bkv; av[u] = bvv; }
#pragma unroll 4
    for (int rr = 0; rr < HID; ++rr) {
        float wq = Wq[rr * HID + t], wk = Wk[rr * HID + t], wv = Wv[rr * HID + t];
#pragma unroll
        for (int u = 0; u < 8; ++u) {
            float x = s_h[u][rr];
            aq[u] = fmaf(x, wq, aq[u]);
            ak[u] = fmaf(x, wk, ak[u]);
            av[u] = fmaf(x, wv, av[u]);
        }
    }
    int h = t >> 5, d = t & 31;
#pragma unroll
    for (int u = 0; u < 8; ++u) {
        size_t idx = ((size_t)(b * HEADS + h) * NN + i0 + u) * HDIM + d;
        q[idx] = aq[u]; k[idx] = ak[u]; v[idx] = av[u];
    }
}

// ---------- kernel 2: fused eb (dual MFMA) + scores + softmax + attn@V ----------
// One block = (b, i0..i0+3).  512 blocks, 4 waves; wave w owns q-row i0+w.
__global__ __launch_bounds__(256, 2) void k_attn(
    const float* __restrict__ edge_x, const int* __restrict__ emask,
    const float* __restrict__ q, const float* __restrict__ k, const float* __restrict__ v,
    const unsigned short* __restrict__ W1P, const unsigned short* __restrict__ W2P,
    const float* __restrict__ be1, const float* __restrict__ be2,
    float* __restrict__ attn, float* __restrict__ ao) {
    int bid = blockIdx.x;
    int b = bid >> 7, i0 = (bid & 127) << 2;
    int t = threadIdx.x;
    int w = t >> 6, lane = t & 63;
    int qq = lane >> 4, r = lane & 15;

    __shared__ __align__(16) float s_sc[HEADS][NN][4];        // 64 KB  [h][j][qi]
    __shared__ __align__(16) float s_q[4][HID];               // 4 KB
    __shared__ __align__(16) unsigned short h_sub[4][16][64]; // 8 KB (per-wave 2KB)
    __shared__ __align__(16) float s_be1[HID];                // 1 KB

    // ---- P0: stage q rows + be1 ----
#pragma unroll
    for (int u = 0; u < 4; ++u) {
        int h = t >> 5, d = t & 31;
        s_q[u][t] = q[((size_t)(b * HEADS + h) * NN + (i0 + u)) * HDIM + d];
    }
    s_be1[t] = be1[t];

    // preload weight fragments into registers
    bf16x8 W1Pr[16];
#pragma unroll
    for (int ut = 0; ut < 16; ++ut)
        W1Pr[ut] = *(const bf16x8*)(W1P + ((size_t)ut * 64 + lane) * 8);
    bf16x8 w2f[8];
#pragma unroll
    for (int kt = 0; kt < 8; ++kt)
        w2f[kt] = *(const bf16x8*)(W2P + ((size_t)kt * 64 + lane) * 8);
    float be2r = (r < 8) ? be2[r] : 0.f;
    __syncthreads();

    // ---- P1: edge-bias MLP, both layers on MFMA ----
    {
        size_t rowbase = ((size_t)b * NN + i0 + w) * NN;   // edge rows for qi=w
        unsigned sw = (unsigned)((r & 7) << 4);
        char* hb = (char*)(&h_sub[w][0][0]) + r * 128;
        for (int c = 0; c < 32; ++c) {
            size_t g = rowbase + (size_t)(c * 16 + r);
            const float4* px = (const float4*)(edge_x + g * EDIM + (qq & 1) * 8);
            float4 x0 = px[0], x1 = px[1];
            bf16x8 bhi, blo;
            {
                float xs[8] = {x0.x, x0.y, x0.z, x0.w, x1.x, x1.y, x1.z, x1.w};
#pragma unroll
                for (int j = 0; j < 8; ++j) {
                    unsigned short h16 = bf16_hi(xs[j]);
                    bhi[j] = (short)h16;
                    blo[j] = (short)bf16_hi(xs[j] - bf16_f(h16));
                }
            }
            f32x4 acc = {be2r, be2r, be2r, be2r};
#pragma unroll
            for (int kt = 0; kt < 8; ++kt) {
                f32x4 b0 = *(const f32x4*)(&s_be1[(2 * kt) * 16 + qq * 4]);
                f32x4 b1 = *(const f32x4*)(&s_be1[(2 * kt + 1) * 16 + qq * 4]);
                f32x4 c0 = __builtin_amdgcn_mfma_f32_16x16x32_bf16(W1Pr[2 * kt], bhi, b0, 0, 0, 0);
                c0 = __builtin_amdgcn_mfma_f32_16x16x32_bf16(W1Pr[2 * kt], blo, c0, 0, 0, 0);
                f32x4 c1 = __builtin_amdgcn_mfma_f32_16x16x32_bf16(W1Pr[2 * kt + 1], bhi, b1, 0, 0, 0);
                c1 = __builtin_amdgcn_mfma_f32_16x16x32_bf16(W1Pr[2 * kt + 1], blo, c1, 0, 0, 0);
                // relu + bf16(RNE) + transpose via swizzled LDS
                uint2 w0, w1;
                w0.x = (unsigned)bf16_rn(fmaxf(c0[0], 0.f)) | ((unsigned)bf16_rn(fmaxf(c0[1], 0.f)) << 16);
                w0.y = (unsigned)bf16_rn(fmaxf(c0[2], 0.f)) | ((unsigned)bf16_rn(fmaxf(c0[3], 0.f)) << 16);
                w1.x = (unsigned)bf16_rn(fmaxf(c1[0], 0.f)) | ((unsigned)bf16_rn(fmaxf(c1[1], 0.f)) << 16);
                w1.y = (unsigned)bf16_rn(fmaxf(c1[2], 0.f)) | ((unsigned)bf16_rn(fmaxf(c1[3], 0.f)) << 16);
                *(uint2*)(hb + (((unsigned)(qq * 8)) ^ sw)) = w0;
                *(uint2*)(hb + (((unsigned)(32 + qq * 8)) ^ sw)) = w1;
                bf16x8 af = *(const bf16x8*)(hb + (((unsigned)(qq * 16)) ^ sw));
                acc = __builtin_amdgcn_mfma_f32_16x16x32_bf16(af, w2f[kt], acc, 0, 0, 0);
            }
            if (r < 8) {
                int j = c * 16 + qq * 4;
                s_sc[r][j + 0][w] = acc[0];
                s_sc[r][j + 1][w] = acc[1];
                s_sc[r][j + 2][w] = acc[2];
                s_sc[r][j + 3][w] = acc[3];
            }
        }
    }
    __syncthreads();

    // ---- P2: QK^T + leaky relu + eb + mask ----
    const float scale = 0.17677669529663687f;  // 1/sqrt(32)
#pragma unroll
    for (int rep = 0; rep < 16; ++rep) {
        int idx = rep * 256 + t;
        int h = idx >> 9, j = idx & (NN - 1);
        const float4* kr = (const float4*)(k + (((size_t)b * HEADS + h) * NN + j) * HDIM);
        float4 kk[8];
#pragma unroll
        for (int d4 = 0; d4 < 8; ++d4) kk[d4] = kr[d4];
        float4 sv = *(float4*)(&s_sc[h][j][0]);
        float accq[4];
#pragma unroll
        for (int qi = 0; qi < 4; ++qi) {
            const float4* qp = (const float4*)(&s_q[qi][h * HDIM]);
            float a = 0.f;
#pragma unroll
            for (int d4 = 0; d4 < 8; ++d4) {
                float4 qv = qp[d4];
                a = fmaf(qv.x, kk[d4].x, a);
                a = fmaf(qv.y, kk[d4].y, a);
                a = fmaf(qv.z, kk[d4].z, a);
                a = fmaf(qv.w, kk[d4].w, a);
            }
            accq[qi] = a;
        }
        float4 so;
#pragma unroll
        for (int qi = 0; qi < 4; ++qi) {
            float s = accq[qi] * scale;
            s = s > 0.f ? s : 0.2f * s;
            s += (qi == 0) ? sv.x : (qi == 1) ? sv.y : (qi == 2) ? sv.z : sv.w;
            bool valid = (emask[((size_t)b * NN + i0 + qi) * NN + j] != 0) || (j == i0 + qi);
            float res = valid ? s : -1e9f;
            if (qi == 0) so.x = res; else if (qi == 1) so.y = res; else if (qi == 2) so.z = res; else so.w = res;
        }
        *(float4*)(&s_sc[h][j][0]) = so;
    }
    __syncthreads();

    // ---- P3: softmax per (qi=w, h) row + write attn ----
    {
        int qi = w;
#pragma unroll
        for (int h = 0; h < HEADS; ++h) {
            float vals[8];
            float mx = -3e38f;
#pragma unroll
            for (int l = 0; l < 8; ++l) {
                vals[l] = s_sc[h][lane + l * 64][qi];
                mx = fmaxf(mx, vals[l]);
            }
#pragma unroll
            for (int off = 32; off > 0; off >>= 1) mx = fmaxf(mx, __shfl_xor(mx, off));
            float sum = 0.f;
#pragma unroll
            for (int l = 0; l < 8; ++l) { vals[l] = __expf(vals[l] - mx); sum += vals[l]; }
#pragma unroll
            for (int off = 32; off > 0; off >>= 1) sum += __shfl_xor(sum, off);
            float inv = 1.f / sum;
            float* arow = attn + (((size_t)b * HEADS + h) * NN + (i0 + qi)) * NN;
#pragma unroll
            for (int l = 0; l < 8; ++l) {
                float a = vals[l] * inv;
                arow[lane + l * 64] = a;
                s_sc[h][lane + l * 64][qi] = a;
            }
        }
    }
    __syncthreads();

    // ---- P4: attn @ V ----
    {
        int h = t >> 5, d = t & 31;
        const float* vp = v + (((size_t)b * HEADS + h) * NN) * HDIM + d;
        float a0 = 0.f, a1 = 0.f, a2 = 0.f, a3 = 0.f;
#pragma unroll 8
        for (int j = 0; j < NN; ++j) {
            float vv = vp[(size_t)j * HDIM];
            float4 aw = *(float4*)(&s_sc[h][j][0]);
            a0 = fmaf(aw.x, vv, a0);
            a1 = fmaf(aw.y, vv, a1);
            a2 = fmaf(aw.z, vv, a2);
            a3 = fmaf(aw.w, vv, a3);
        }
        ao[((size_t)b * NN + i0 + 0) * HID + t] = a0;
        ao[((size_t)b * NN + i0 + 1) * HID + t] = a1;
        ao[((size_t)b * NN + i0 + 2) * HID + t] = a2;
        ao[((size_t)b * NN + i0 + 3) * HID + t] = a3;
    }
}

// ---------- kernel 3: Wo + residual + LayerNorm + relu, 8 rows/block ----------
__global__ __launch_bounds__(256) void k_final(
    const float* __restrict__ ao, const float* __restrict__ node_h,
    const float* __restrict__ Wo, const float* __restrict__ bo,
    const float* __restrict__ ln_g, const float* __restrict__ ln_b,
    float* __restrict__ out) {
    int blk = blockIdx.x;           // 256 blocks
    size_t bi0 = (size_t)blk * 8;
    int t = threadIdx.x;
    __shared__ __align__(16) float s_a[8][HID];
    __shared__ float s_red[8][4][2];
#pragma unroll
    for (int u = 0; u < 8; ++u)
        s_a[u][t] = ao[(bi0 + u) * HID + t];
    __syncthreads();
    float bov = bo[t];
    float o[8];
#pragma unroll
    for (int u = 0; u < 8; ++u) o[u] = bov;
#pragma unroll 4
    for (int rr = 0; rr < HID; ++rr) {
        float wo = Wo[rr * HID + t];
#pragma unroll
        for (int u = 0; u < 8; ++u) o[u] = fmaf(s_a[u][rr], wo, o[u]);
    }
    float g = ln_g[t], bb = ln_b[t];
    int wave = t >> 6, ln = t & 63;
    float x[8];
#pragma unroll
    for (int u = 0; u < 8; ++u) {
        x[u] = node_h[(bi0 + u) * HID + t] + o[u];
        float s1 = x[u], s2 = x[u] * x[u];
#pragma unroll
        for (int off = 32; off > 0; off >>= 1) { s1 += __shfl_xor(s1, off); s2 += __shfl_xor(s2, off); }
        if (ln == 0) { s_red[u][wave][0] = s1; s_red[u][wave][1] = s2; }
    }
    __syncthreads();
#pragma unroll
    for (int u = 0; u < 8; ++u) {
        float s1 = s_red[u][0][0] + s_red[u][1][0] + s_red[u][2][0] + s_red[u][3][0];
        float s2 = s_red[u][0][1] + s_red[u][1][1] + s_red[u][2][1] + s_red[u][3][1];
        float mean = s1 * (1.f / HID);
        float var = s2 * (1.f / HID) - mean * mean;
        float inv = rsqrtf(var + 1e-5f);
        float y = (x[u] - mean) * inv * g + bb;
        out[(bi0 + u) * HID + t] = fmaxf(y, 0.f);
    }
}

extern "C" void kernel_launch(void* const* d_in, const int* in_sizes, int n_in,
                              void* d_out, int out_size, void* d_ws, size_t ws_size,
                              hipStream_t stream) {
    const float* node_h = (const float*)d_in[0];
    const float* edge_x = (const float*)d_in[1];
    const int*   emask  = (const int*)d_in[2];
    const float* Wq = (const float*)d_in[3];
    const float* bq = (const float*)d_in[4];
    const float* Wk = (const float*)d_in[5];
    const float* bk = (const float*)d_in[6];
    const float* Wv = (const float*)d_in[7];
    const float* bv = (const float*)d_in[8];
    const float* We1 = (const float*)d_in[9];
    const float* be1 = (const float*)d_in[10];
    const float* We2 = (const float*)d_in[11];
    const float* be2 = (const float*)d_in[12];
    const float* Wo = (const float*)d_in[13];
    const float* bo = (const float*)d_in[14];
    const float* ln_g = (const float*)d_in[15];
    const float* ln_b = (const float*)d_in[16];

    float* out_x  = (float*)d_out;                              // [4,512,256]
    float* out_at = (float*)d_out + (size_t)BATCH * NN * HID;   // [4,8,512,512]

    float* ws = (float*)d_ws;
    float* q    = ws;                                  // 524288 floats
    float* kbuf = ws + 524288;
    float* vbuf = ws + 1048576;
    float* ao   = ws + 1572864;
    unsigned short* W1P = (unsigned short*)(ws + 2097152);  // 8192 ushorts
    unsigned short* W2P = W1P + 8192;                       // 4096 ushorts

    const int NBI = BATCH * NN;  // 2048

    hipLaunchKernelGGL(k_pack, dim3(1), dim3(256), 0, stream, We1, We2, W1P, W2P);
    hipLaunchKernelGGL(k_qkv, dim3(NBI / 8), dim3(256), 0, stream,
                       node_h, Wq, bq, Wk, bk, Wv, bv, q, kbuf, vbuf);
    hipLaunchKernelGGL(k_attn, dim3(NBI / 4), dim3(256), 0, stream,
                       edge_x, emask, q, kbuf, vbuf, W1P, W2P, be1, be2, out_at, ao);
    hipLaunchKernelGGL(k_final, dim3(NBI / 8), dim3(256), 0, stream,
                       ao, node_h, Wo, bo, ln_g, ln_b, out_x);
}

// Round 4
// 160.525 us; speedup vs baseline: 2.4653x; 1.1702x over previous
//
#include <hip/hip_runtime.h>

#define BATCH 4
#define NN 512
#define HID 256
#define EDIM 16
#define HEADS 8
#define HDIM 32

typedef __attribute__((ext_vector_type(8))) short bf16x8;
typedef __attribute__((ext_vector_type(4))) float f32x4;

__device__ inline unsigned short bf16_hi(float x){ return (unsigned short)(__float_as_uint(x)>>16); }
__device__ inline float bf16_f(unsigned short s){ return __uint_as_float(((unsigned)s)<<16); }
__device__ inline unsigned short bf16_rn(float x){
    unsigned u = __float_as_uint(x);
    unsigned r = u + 0x7FFFu + ((u>>16)&1u);
    return (unsigned short)(r>>16);
}
__device__ inline unsigned cvt_pk_bf16(float a, float b){
    unsigned d;
    asm("v_cvt_pk_bf16_f32 %0, %1, %2" : "=v"(d) : "v"(a), "v"(b));
    return d;
}

// ---------- kernel 0: pack W1 (K=32: [W1hi(16); W1lo(15); be1]) + W2 bf16 B-frags ----------
// W1P: lane l=16q+r of tile ut holds A[row r -> unit ut*16+r][k=q*8+j]:
//   k<16: hi(We1[k][unit]); 16<=k<31: rn(lo(We1[k-16][unit])); k=31: rn(be1[unit]).
// B side duplicates rn(x[e]) in both K halves, with slot31 = 1.0 -> C = W1_full*x + be1.
__global__ void k_pack(const float* __restrict__ We1, const float* __restrict__ be1,
                       const float* __restrict__ We2,
                       unsigned short* __restrict__ W1P, unsigned short* __restrict__ W2P) {
    int t = threadIdx.x;  // 256
#pragma unroll
    for (int rep = 0; rep < 4; ++rep) {
        int p = rep * 256 + t;          // (ut, lane)
        int ut = p >> 6, lane = p & 63;
        int q = lane >> 4, r = lane & 15;
        int unit = ut * 16 + r;
#pragma unroll
        for (int j = 0; j < 8; ++j) {
            int k = q * 8 + j;
            unsigned short ov;
            if (k < 16) ov = bf16_hi(We1[k * HID + unit]);
            else if (k < 31) {
                float v = We1[(k - 16) * HID + unit];
                ov = bf16_rn(v - bf16_f(bf16_hi(v)));
            } else ov = bf16_rn(be1[unit]);
            W1P[p * 8 + j] = ov;
        }
    }
#pragma unroll
    for (int rep = 0; rep < 2; ++rep) {
        int p = rep * 256 + t;          // (kt, lane)
        int kt = p >> 6, lane = p & 63;
        int q = lane >> 4, r = lane & 15;
#pragma unroll
        for (int jj = 0; jj < 8; ++jj) {
            int unit = kt * 32 + q * 8 + jj;
            W2P[p * 8 + jj] = (r < 8) ? bf16_rn(We2[unit * HEADS + r]) : (unsigned short)0;
        }
    }
}

// ---------- kernel 1: QKV projections, 4 rows/block ----------
__global__ __launch_bounds__(256) void k_qkv(
    const float* __restrict__ node_h,
    const float* __restrict__ Wq, const float* __restrict__ bq,
    const float* __restrict__ Wk, const float* __restrict__ bk,
    const float* __restrict__ Wv, const float* __restrict__ bv,
    float* __restrict__ q, float* __restrict__ k, float* __restrict__ v) {
    int blk = blockIdx.x;           // 512 blocks
    int b = blk >> 7, i0 = (blk & 127) << 2;
    int t = threadIdx.x;
    __shared__ __align__(16) float s_h[4][HID];
#pragma unroll
    for (int u = 0; u < 4; ++u)
        s_h[u][t] = node_h[((size_t)b * NN + i0 + u) * HID + t];
    __syncthreads();
    float aq[4], ak[4], av[4];
    float bqv = bq[t], bkv = bk[t], bvv = bv[t];
#pragma unroll
    for (int u = 0; u < 4; ++u) { aq[u] = bqv; ak[u] = bkv; av[u] = bvv; }
#pragma unroll 4
    for (int rr = 0; rr < HID; ++rr) {
        float wq = Wq[rr * HID + t], wk = Wk[rr * HID + t], wv = Wv[rr * HID + t];
#pragma unroll
        for (int u = 0; u < 4; ++u) {
            float x = s_h[u][rr];
            aq[u] = fmaf(x, wq, aq[u]);
            ak[u] = fmaf(x, wk, ak[u]);
            av[u] = fmaf(x, wv, av[u]);
        }
    }
    int h = t >> 5, d = t & 31;
#pragma unroll
    for (int u = 0; u < 4; ++u) {
        size_t idx = ((size_t)(b * HEADS + h) * NN + i0 + u) * HDIM + d;
        q[idx] = aq[u]; k[idx] = ak[u]; v[idx] = av[u];
    }
}

// ---------- kernel 2: fused eb (MFMA both layers) + scores + softmax + attn@V ----------
// One block = (b, i0..i0+3). 512 blocks, 4 waves; wave w owns q-row i0+w.
__global__ __launch_bounds__(256, 2) void k_attn(
    const float* __restrict__ edge_x, const int* __restrict__ emask,
    const float* __restrict__ q, const float* __restrict__ k, const float* __restrict__ v,
    const unsigned short* __restrict__ W1P, const unsigned short* __restrict__ W2P,
    const float* __restrict__ be2,
    float* __restrict__ attn, float* __restrict__ ao) {
    int bid = blockIdx.x;
    int b = bid >> 7, i0 = (bid & 127) << 2;
    int t = threadIdx.x;
    int w = t >> 6, lane = t & 63;
    int q2 = lane >> 4, r = lane & 15;

    __shared__ __align__(16) float s_sc[HEADS][4][NN];   // 64 KB  [h][qi][j]
    __shared__ __align__(16) float s_q[4][HID];          // 4 KB
    __shared__ __align__(16) char  s_hb[4][2048];        // 8 KB, wave-private 2KB

    // ---- P0: stage q rows ----
#pragma unroll
    for (int u = 0; u < 4; ++u) {
        int hh = t >> 5, d = t & 31;
        s_q[u][t] = q[((size_t)(b * HEADS + hh) * NN + (i0 + u)) * HDIM + d];
    }

    // preload weight fragments
    bf16x8 W1Pr[16];
#pragma unroll
    for (int ut = 0; ut < 16; ++ut)
        W1Pr[ut] = *(const bf16x8*)(W1P + ((size_t)ut * 64 + lane) * 8);
    bf16x8 w2f[8];
#pragma unroll
    for (int kt = 0; kt < 8; ++kt)
        w2f[kt] = *(const bf16x8*)(W2P + ((size_t)kt * 64 + lane) * 8);
    float be2r = (r < 8) ? be2[r] : 0.f;

    // ---- P1: edge-bias MLP, both layers MFMA, conflict-free wave-private h transpose ----
    {
        size_t xbase = (((size_t)b * NN + i0 + w) * NN) * EDIM + (size_t)((q2 & 1) * 8);
        char* hb = &s_hb[w][0];
        const f32x4 zero4 = {0.f, 0.f, 0.f, 0.f};
        for (int c = 0; c < 32; ++c) {
            const float4* px = (const float4*)(edge_x + xbase + (size_t)(c * 16 + r) * EDIM);
            float4 x0 = px[0], x1 = px[1];
            unsigned u0 = cvt_pk_bf16(x0.x, x0.y);
            unsigned u1 = cvt_pk_bf16(x0.z, x0.w);
            unsigned u2 = cvt_pk_bf16(x1.x, x1.y);
            unsigned u3 = cvt_pk_bf16(x1.z, x1.w);
            if (q2 == 3) u3 = (u3 & 0xFFFFu) | 0x3F800000u;   // slot31 = 1.0 (be1)
            int4 bxi; bxi.x = u0; bxi.y = u1; bxi.z = u2; bxi.w = u3;
            bf16x8 bx = *(bf16x8*)&bxi;

            f32x4 acc = {be2r, be2r, be2r, be2r};
#pragma unroll
            for (int qt = 0; qt < 4; ++qt) {          // 4 tiles -> 2 kt per quarter
#pragma unroll
                for (int u2i = 0; u2i < 4; ++u2i) {
                    int ut = qt * 4 + u2i;
                    f32x4 cc = __builtin_amdgcn_mfma_f32_16x16x32_bf16(W1Pr[ut], bx, zero4, 0, 0, 0);
                    unsigned p01 = cvt_pk_bf16(fmaxf(cc[0], 0.f), fmaxf(cc[1], 0.f));
                    unsigned p23 = cvt_pk_bf16(fmaxf(cc[2], 0.f), fmaxf(cc[3], 0.f));
                    int ktl = (ut >> 1) & 1;
                    unsigned off = (unsigned)(ktl * 1024 + (16 * ((ut & 1) * 2 + (q2 >> 1)) + r) * 16 + (q2 & 1) * 8);
                    uint2 wv; wv.x = p01; wv.y = p23;
                    *(uint2*)(hb + off) = wv;          // conflict-free b64
                }
#pragma unroll
                for (int k2 = 0; k2 < 2; ++k2) {
                    bf16x8 af = *(const bf16x8*)(hb + k2 * 1024 + lane * 16);  // linear b128
                    acc = __builtin_amdgcn_mfma_f32_16x16x32_bf16(af, w2f[qt * 2 + k2], acc, 0, 0, 0);
                }
            }
            if (r < 8)
                *(f32x4*)&s_sc[r][w][c * 16 + q2 * 4] = acc;   // b128, head r, rows q2*4+reg
        }
    }
    __syncthreads();

    // ---- P2: QK^T + leaky relu + eb + mask ----
    const float scale = 0.17677669529663687f;  // 1/sqrt(32)
#pragma unroll
    for (int rep = 0; rep < 16; ++rep) {
        int idx = rep * 256 + t;
        int h = idx >> 9, j = idx & (NN - 1);
        const float4* kr = (const float4*)(k + (((size_t)b * HEADS + h) * NN + j) * HDIM);
        float4 kk[8];
#pragma unroll
        for (int d4 = 0; d4 < 8; ++d4) kk[d4] = kr[d4];
#pragma unroll
        for (int qi = 0; qi < 4; ++qi) {
            const float4* qp = (const float4*)(&s_q[qi][h * HDIM]);
            float a = 0.f;
#pragma unroll
            for (int d4 = 0; d4 < 8; ++d4) {
                float4 qv = qp[d4];
                a = fmaf(qv.x, kk[d4].x, a);
                a = fmaf(qv.y, kk[d4].y, a);
                a = fmaf(qv.z, kk[d4].z, a);
                a = fmaf(qv.w, kk[d4].w, a);
            }
            float s = a * scale;
            s = s > 0.f ? s : 0.2f * s;
            s += s_sc[h][qi][j];
            bool valid = (emask[((size_t)b * NN + i0 + qi) * NN + j] != 0) || (j == i0 + qi);
            s_sc[h][qi][j] = valid ? s : -1e9f;
        }
    }
    __syncthreads();

    // ---- P3: softmax per (qi=w, h) row + write attn ----
    {
#pragma unroll
        for (int h = 0; h < HEADS; ++h) {
            float vals[8];
            float mx = -3e38f;
#pragma unroll
            for (int l = 0; l < 8; ++l) {
                vals[l] = s_sc[h][w][lane + l * 64];
                mx = fmaxf(mx, vals[l]);
            }
#pragma unroll
            for (int off = 32; off > 0; off >>= 1) mx = fmaxf(mx, __shfl_xor(mx, off));
            float sum = 0.f;
#pragma unroll
            for (int l = 0; l < 8; ++l) { vals[l] = __expf(vals[l] - mx); sum += vals[l]; }
#pragma unroll
            for (int off = 32; off > 0; off >>= 1) sum += __shfl_xor(sum, off);
            float inv = 1.f / sum;
            float* arow = attn + (((size_t)b * HEADS + h) * NN + (i0 + w)) * NN;
#pragma unroll
            for (int l = 0; l < 8; ++l) {
                float a = vals[l] * inv;
                arow[lane + l * 64] = a;
                s_sc[h][w][lane + l * 64] = a;
            }
        }
    }
    __syncthreads();

    // ---- P4: attn @ V (4 j per iter, b128 broadcast LDS reads) ----
    {
        int h = t >> 5, d = t & 31;
        const float* vp = v + ((size_t)(b * HEADS + h) * NN) * HDIM + d;
        float a0 = 0.f, a1 = 0.f, a2 = 0.f, a3 = 0.f;
        for (int j = 0; j < NN; j += 4) {
            float vv0 = vp[(size_t)(j + 0) * HDIM];
            float vv1 = vp[(size_t)(j + 1) * HDIM];
            float vv2 = vp[(size_t)(j + 2) * HDIM];
            float vv3 = vp[(size_t)(j + 3) * HDIM];
            f32x4 e0 = *(f32x4*)&s_sc[h][0][j];
            f32x4 e1 = *(f32x4*)&s_sc[h][1][j];
            f32x4 e2 = *(f32x4*)&s_sc[h][2][j];
            f32x4 e3 = *(f32x4*)&s_sc[h][3][j];
            a0 = fmaf(e0[0], vv0, a0); a0 = fmaf(e0[1], vv1, a0); a0 = fmaf(e0[2], vv2, a0); a0 = fmaf(e0[3], vv3, a0);
            a1 = fmaf(e1[0], vv0, a1); a1 = fmaf(e1[1], vv1, a1); a1 = fmaf(e1[2], vv2, a1); a1 = fmaf(e1[3], vv3, a1);
            a2 = fmaf(e2[0], vv0, a2); a2 = fmaf(e2[1], vv1, a2); a2 = fmaf(e2[2], vv2, a2); a2 = fmaf(e2[3], vv3, a2);
            a3 = fmaf(e3[0], vv0, a3); a3 = fmaf(e3[1], vv1, a3); a3 = fmaf(e3[2], vv2, a3); a3 = fmaf(e3[3], vv3, a3);
        }
        ao[((size_t)b * NN + i0 + 0) * HID + t] = a0;
        ao[((size_t)b * NN + i0 + 1) * HID + t] = a1;
        ao[((size_t)b * NN + i0 + 2) * HID + t] = a2;
        ao[((size_t)b * NN + i0 + 3) * HID + t] = a3;
    }
}

// ---------- kernel 3: Wo + residual + LayerNorm + relu, 4 rows/block ----------
__global__ __launch_bounds__(256) void k_final(
    const float* __restrict__ ao, const float* __restrict__ node_h,
    const float* __restrict__ Wo, const float* __restrict__ bo,
    const float* __restrict__ ln_g, const float* __restrict__ ln_b,
    float* __restrict__ out) {
    int blk = blockIdx.x;           // 512 blocks
    size_t bi0 = (size_t)blk * 4;
    int t = threadIdx.x;
    __shared__ __align__(16) float s_a[4][HID];
    __shared__ float s_red[4][4][2];
#pragma unroll
    for (int u = 0; u < 4; ++u)
        s_a[u][t] = ao[(bi0 + u) * HID + t];
    __syncthreads();
    float bov = bo[t];
    float o[4];
#pragma unroll
    for (int u = 0; u < 4; ++u) o[u] = bov;
#pragma unroll 4
    for (int rr = 0; rr < HID; ++rr) {
        float wo = Wo[rr * HID + t];
#pragma unroll
        for (int u = 0; u < 4; ++u) o[u] = fmaf(s_a[u][rr], wo, o[u]);
    }
    float g = ln_g[t], bb = ln_b[t];
    int wave = t >> 6, ln = t & 63;
    float x[4];
#pragma unroll
    for (int u = 0; u < 4; ++u) {
        x[u] = node_h[(bi0 + u) * HID + t] + o[u];
        float s1 = x[u], s2 = x[u] * x[u];
#pragma unroll
        for (int off = 32; off > 0; off >>= 1) { s1 += __shfl_xor(s1, off); s2 += __shfl_xor(s2, off); }
        if (ln == 0) { s_red[u][wave][0] = s1; s_red[u][wave][1] = s2; }
    }
    __syncthreads();
#pragma unroll
    for (int u = 0; u < 4; ++u) {
        float s1 = s_red[u][0][0] + s_red[u][1][0] + s_red[u][2][0] + s_red[u][3][0];
        float s2 = s_red[u][0][1] + s_red[u][1][1] + s_red[u][2][1] + s_red[u][3][1];
        float mean = s1 * (1.f / HID);
        float var = s2 * (1.f / HID) - mean * mean;
        float inv = rsqrtf(var + 1e-5f);
        float y = (x[u] - mean) * inv * g + bb;
        out[(bi0 + u) * HID + t] = fmaxf(y, 0.f);
    }
}

extern "C" void kernel_launch(void* const* d_in, const int* in_sizes, int n_in,
                              void* d_out, int out_size, void* d_ws, size_t ws_size,
                              hipStream_t stream) {
    const float* node_h = (const float*)d_in[0];
    const float* edge_x = (const float*)d_in[1];
    const int*   emask  = (const int*)d_in[2];
    const float* Wq = (const float*)d_in[3];
    const float* bq = (const float*)d_in[4];
    const float* Wk = (const float*)d_in[5];
    const float* bk = (const float*)d_in[6];
    const float* Wv = (const float*)d_in[7];
    const float* bv = (const float*)d_in[8];
    const float* We1 = (const float*)d_in[9];
    const float* be1 = (const float*)d_in[10];
    const float* We2 = (const float*)d_in[11];
    const float* be2 = (const float*)d_in[12];
    const float* Wo = (const float*)d_in[13];
    const float* bo = (const float*)d_in[14];
    const float* ln_g = (const float*)d_in[15];
    const float* ln_b = (const float*)d_in[16];

    float* out_x  = (float*)d_out;                              // [4,512,256]
    float* out_at = (float*)d_out + (size_t)BATCH * NN * HID;   // [4,8,512,512]

    float* ws = (float*)d_ws;
    float* q    = ws;                                  // 524288 floats
    float* kbuf = ws + 524288;
    float* vbuf = ws + 1048576;
    float* ao   = ws + 1572864;
    unsigned short* W1P = (unsigned short*)(ws + 2097152);  // 8192 ushorts
    unsigned short* W2P = W1P + 8192;                       // 4096 ushorts

    const int NBI = BATCH * NN;  // 2048

    hipLaunchKernelGGL(k_pack, dim3(1), dim3(256), 0, stream, We1, be1, We2, W1P, W2P);
    hipLaunchKernelGGL(k_qkv, dim3(NBI / 4), dim3(256), 0, stream,
                       node_h, Wq, bq, Wk, bk, Wv, bv, q, kbuf, vbuf);
    hipLaunchKernelGGL(k_attn, dim3(NBI / 4), dim3(256), 0, stream,
                       edge_x, emask, q, kbuf, vbuf, W1P, W2P, be2, out_at, ao);
    hipLaunchKernelGGL(k_final, dim3(NBI / 4), dim3(256), 0, stream,
                       ao, node_h, Wo, bo, ln_g, ln_b, out_x);
}

// Round 5
// 147.304 us; speedup vs baseline: 2.6866x; 1.0898x over previous
//
#include <hip/hip_runtime.h>

#define BATCH 4
#define NN 512
#define HID 256
#define EDIM 16
#define HEADS 8
#define HDIM 32

typedef __attribute__((ext_vector_type(8))) short bf16x8;
typedef __attribute__((ext_vector_type(4))) float f32x4;

__device__ inline unsigned short bf16_hi(float x){ return (unsigned short)(__float_as_uint(x)>>16); }
__device__ inline float bf16_f(unsigned short s){ return __uint_as_float(((unsigned)s)<<16); }
__device__ inline unsigned short bf16_rn(float x){
    unsigned u = __float_as_uint(x);
    unsigned r = u + 0x7FFFu + ((u>>16)&1u);
    return (unsigned short)(r>>16);
}
__device__ inline unsigned cvt_pk_bf16(float a, float b){
    unsigned d;
    asm("v_cvt_pk_bf16_f32 %0, %1, %2" : "=v"(d) : "v"(a), "v"(b));
    return d;
}
// split 8 floats into hi (trunc) and lo (RNE of remainder) bf16x8 fragments
__device__ inline void hilo8(float4 A, float4 B, bf16x8& hi, bf16x8& lo){
    float xs[8] = {A.x,A.y,A.z,A.w,B.x,B.y,B.z,B.w};
    unsigned hu[4], lu[4];
#pragma unroll
    for (int p = 0; p < 4; ++p){
        unsigned u0 = __float_as_uint(xs[2*p]), u1 = __float_as_uint(xs[2*p+1]);
        float h0 = __uint_as_float(u0 & 0xFFFF0000u);
        float h1 = __uint_as_float(u1 & 0xFFFF0000u);
        hu[p] = (u0 >> 16) | (u1 & 0xFFFF0000u);
        lu[p] = cvt_pk_bf16(xs[2*p] - h0, xs[2*p+1] - h1);
    }
    int4 hv; hv.x = hu[0]; hv.y = hu[1]; hv.z = hu[2]; hv.w = hu[3];
    int4 lv; lv.x = lu[0]; lv.y = lu[1]; lv.z = lu[2]; lv.w = lu[3];
    hi = *(bf16x8*)&hv; lo = *(bf16x8*)&lv;
}

// ---------- kernel 0: pack W1 (K=32: [W1hi(16); W1lo(15); be1]) + W2 bf16 B-frags ----------
__global__ void k_pack(const float* __restrict__ We1, const float* __restrict__ be1,
                       const float* __restrict__ We2,
                       unsigned short* __restrict__ W1P, unsigned short* __restrict__ W2P) {
    int t = threadIdx.x;  // 256
#pragma unroll
    for (int rep = 0; rep < 4; ++rep) {
        int p = rep * 256 + t;          // (ut, lane)
        int ut = p >> 6, lane = p & 63;
        int q = lane >> 4, r = lane & 15;
        int unit = ut * 16 + r;
#pragma unroll
        for (int j = 0; j < 8; ++j) {
            int k = q * 8 + j;
            unsigned short ov;
            if (k < 16) ov = bf16_hi(We1[k * HID + unit]);
            else if (k < 31) {
                float v = We1[(k - 16) * HID + unit];
                ov = bf16_rn(v - bf16_f(bf16_hi(v)));
            } else ov = bf16_rn(be1[unit]);
            W1P[p * 8 + j] = ov;
        }
    }
#pragma unroll
    for (int rep = 0; rep < 2; ++rep) {
        int p = rep * 256 + t;          // (kt, lane)
        int kt = p >> 6, lane = p & 63;
        int q = lane >> 4, r = lane & 15;
#pragma unroll
        for (int jj = 0; jj < 8; ++jj) {
            int unit = kt * 32 + q * 8 + jj;
            W2P[p * 8 + jj] = (r < 8) ? bf16_rn(We2[unit * HEADS + r]) : (unsigned short)0;
        }
    }
}

// ---------- kernel 1: QKV projections, 4 rows/block; q,k:[b,h,i,d]  vT:[b,h,d,i] ----------
__global__ __launch_bounds__(256) void k_qkv(
    const float* __restrict__ node_h,
    const float* __restrict__ Wq, const float* __restrict__ bq,
    const float* __restrict__ Wk, const float* __restrict__ bk,
    const float* __restrict__ Wv, const float* __restrict__ bv,
    float* __restrict__ q, float* __restrict__ k, float* __restrict__ vT) {
    int blk = blockIdx.x;           // 512 blocks
    int b = blk >> 7, i0 = (blk & 127) << 2;
    int t = threadIdx.x;
    __shared__ __align__(16) float s_h[4][HID];
#pragma unroll
    for (int u = 0; u < 4; ++u)
        s_h[u][t] = node_h[((size_t)b * NN + i0 + u) * HID + t];
    __syncthreads();
    float aq[4], ak[4], av[4];
    float bqv = bq[t], bkv = bk[t], bvv = bv[t];
#pragma unroll
    for (int u = 0; u < 4; ++u) { aq[u] = bqv; ak[u] = bkv; av[u] = bvv; }
#pragma unroll 4
    for (int rr = 0; rr < HID; ++rr) {
        float wq = Wq[rr * HID + t], wk = Wk[rr * HID + t], wv = Wv[rr * HID + t];
#pragma unroll
        for (int u = 0; u < 4; ++u) {
            float x = s_h[u][rr];
            aq[u] = fmaf(x, wq, aq[u]);
            ak[u] = fmaf(x, wk, ak[u]);
            av[u] = fmaf(x, wv, av[u]);
        }
    }
    int h = t >> 5, d = t & 31;
#pragma unroll
    for (int u = 0; u < 4; ++u) {
        size_t idx = ((size_t)(b * HEADS + h) * NN + i0 + u) * HDIM + d;
        q[idx] = aq[u]; k[idx] = ak[u];
        vT[((size_t)(b * HEADS + h) * HDIM + d) * NN + i0 + u] = av[u];
    }
}

// ---------- kernel 2: edge-bias MLP (both layers MFMA) -> eb into d_out attn region ----------
// grid 1024 = (b, i-chunk of 4, j-half). wave w owns q-row i0+w, 16 j-tiles.
__global__ __launch_bounds__(256, 4) void k_eb(
    const float* __restrict__ edge_x,
    const unsigned short* __restrict__ W1P, const unsigned short* __restrict__ W2P,
    const float* __restrict__ be2, float* __restrict__ eb) {
    int bid = blockIdx.x;
    int b = bid >> 8, i0 = ((bid >> 1) & 127) << 2, jh = bid & 1;
    int t = threadIdx.x;
    int w = t >> 6, lane = t & 63;
    int q2 = lane >> 4, r = lane & 15;

    __shared__ __align__(16) char s_hb[4][2048];   // wave-private transpose buffers

    bf16x8 W1Pr[16];
#pragma unroll
    for (int ut = 0; ut < 16; ++ut)
        W1Pr[ut] = *(const bf16x8*)(W1P + ((size_t)ut * 64 + lane) * 8);
    bf16x8 w2f[8];
#pragma unroll
    for (int kt = 0; kt < 8; ++kt)
        w2f[kt] = *(const bf16x8*)(W2P + ((size_t)kt * 64 + lane) * 8);
    float be2r = (r < 8) ? be2[r] : 0.f;

    size_t xbase = (((size_t)b * NN + i0 + w) * NN) * EDIM + (size_t)((q2 & 1) * 8);
    char* hb = &s_hb[w][0];
    const f32x4 zero4 = {0.f, 0.f, 0.f, 0.f};
    for (int c = 0; c < 16; ++c) {
        int cc = jh * 16 + c;
        const float4* px = (const float4*)(edge_x + xbase + (size_t)(cc * 16 + r) * EDIM);
        float4 x0 = px[0], x1 = px[1];
        unsigned u0 = cvt_pk_bf16(x0.x, x0.y);
        unsigned u1 = cvt_pk_bf16(x0.z, x0.w);
        unsigned u2 = cvt_pk_bf16(x1.x, x1.y);
        unsigned u3 = cvt_pk_bf16(x1.z, x1.w);
        if (q2 == 3) u3 = (u3 & 0xFFFFu) | 0x3F800000u;   // slot31 = 1.0 (be1)
        int4 bxi; bxi.x = u0; bxi.y = u1; bxi.z = u2; bxi.w = u3;
        bf16x8 bx = *(bf16x8*)&bxi;

        f32x4 acc = {be2r, be2r, be2r, be2r};
#pragma unroll
        for (int qt = 0; qt < 4; ++qt) {
#pragma unroll
            for (int u2i = 0; u2i < 4; ++u2i) {
                int ut = qt * 4 + u2i;
                f32x4 ch = __builtin_amdgcn_mfma_f32_16x16x32_bf16(W1Pr[ut], bx, zero4, 0, 0, 0);
                unsigned p01 = cvt_pk_bf16(fmaxf(ch[0], 0.f), fmaxf(ch[1], 0.f));
                unsigned p23 = cvt_pk_bf16(fmaxf(ch[2], 0.f), fmaxf(ch[3], 0.f));
                int ktl = (ut >> 1) & 1;
                unsigned off = (unsigned)(ktl * 1024 + (16 * ((ut & 1) * 2 + (q2 >> 1)) + r) * 16 + (q2 & 1) * 8);
                uint2 wv; wv.x = p01; wv.y = p23;
                *(uint2*)(hb + off) = wv;
            }
#pragma unroll
            for (int k2 = 0; k2 < 2; ++k2) {
                bf16x8 af = *(const bf16x8*)(hb + k2 * 1024 + lane * 16);
                acc = __builtin_amdgcn_mfma_f32_16x16x32_bf16(af, w2f[qt * 2 + k2], acc, 0, 0, 0);
            }
        }
        if (r < 8)
            *(f32x4*)(eb + (((size_t)(b * HEADS + r) * NN) + (i0 + w)) * NN + cc * 16 + q2 * 4) = acc;
    }
}

// ---------- kernel 3: scores(MFMA) + softmax + attn@V(MFMA) per (b,h,16 q-rows) ----------
// grid 1024 = (b, h, ic). attn buffer holds eb on entry, final attn on exit.
__global__ __launch_bounds__(256, 3) void k_attn2(
    const int* __restrict__ emask,
    const float* __restrict__ q, const float* __restrict__ k, const float* __restrict__ vT,
    float* attn, float* __restrict__ ao) {
    int bid = blockIdx.x;
    int b = bid >> 8, h = (bid >> 5) & 7, ic = bid & 31;
    int i0 = ic << 4;
    int t = threadIdx.x, w = t >> 6, lane = t & 63;
    int q2 = lane >> 4, r = lane & 15;
    size_t bh = (size_t)b * HEADS + h;

    __shared__ __align__(16) float s_sc[16][516];           // 33024 B
    __shared__ __align__(16) unsigned short s_ab[16][520];  // 16640 B
    __shared__ float s_out[2][16][33];                      // 4224 B

    // Q A-frag (hi/lo): lane 16*q2+r holds Q[row=r][d=q2*8..+7]
    bf16x8 qhi, qlo;
    {
        const float4* qp = (const float4*)(q + ((bh * NN) + i0 + r) * HDIM + q2 * 8);
        hilo8(qp[0], qp[1], qhi, qlo);
    }

    const float scale = 0.17677669529663687f;  // 1/sqrt(32)
    // ---- QK^T + leaky + eb + mask; wave w: j-tiles w*8..w*8+7 ----
    for (int c = 0; c < 8; ++c) {
        int jt = w * 8 + c;
        bf16x8 khi, klo;
        {
            const float4* kp = (const float4*)(k + (bh * NN + jt * 16 + r) * HDIM + q2 * 8);
            hilo8(kp[0], kp[1], khi, klo);
        }
        f32x4 cc = {0.f, 0.f, 0.f, 0.f};
        cc = __builtin_amdgcn_mfma_f32_16x16x32_bf16(qhi, khi, cc, 0, 0, 0);
        cc = __builtin_amdgcn_mfma_f32_16x16x32_bf16(qhi, klo, cc, 0, 0, 0);
        cc = __builtin_amdgcn_mfma_f32_16x16x32_bf16(qlo, khi, cc, 0, 0, 0);
        int j = jt * 16 + r;
#pragma unroll
        for (int reg = 0; reg < 4; ++reg) {
            int row = q2 * 4 + reg;
            int i = i0 + row;
            float s = cc[reg] * scale;
            s = s > 0.f ? s : 0.2f * s;
            s += attn[(bh * NN + i) * NN + j];       // eb
            bool valid = (emask[((size_t)b * NN + i) * NN + j] != 0) || (j == i);
            s_sc[row][j] = valid ? s : -1e9f;
        }
    }
    __syncthreads();

    // ---- softmax: wave w rows w*4..w*4+3; lane owns j = lane*8..lane*8+7 ----
#pragma unroll
    for (int rr = 0; rr < 4; ++rr) {
        int row = w * 4 + rr;
        f32x4 v0 = *(f32x4*)&s_sc[row][lane * 8];
        f32x4 v1 = *(f32x4*)&s_sc[row][lane * 8 + 4];
        float mx = fmaxf(fmaxf(fmaxf(v0[0], v0[1]), fmaxf(v0[2], v0[3])),
                         fmaxf(fmaxf(v1[0], v1[1]), fmaxf(v1[2], v1[3])));
#pragma unroll
        for (int off = 32; off > 0; off >>= 1) mx = fmaxf(mx, __shfl_xor(mx, off));
        float e[8];
        e[0] = __expf(v0[0] - mx); e[1] = __expf(v0[1] - mx);
        e[2] = __expf(v0[2] - mx); e[3] = __expf(v0[3] - mx);
        e[4] = __expf(v1[0] - mx); e[5] = __expf(v1[1] - mx);
        e[6] = __expf(v1[2] - mx); e[7] = __expf(v1[3] - mx);
        float sum = ((e[0] + e[1]) + (e[2] + e[3])) + ((e[4] + e[5]) + (e[6] + e[7]));
#pragma unroll
        for (int off = 32; off > 0; off >>= 1) sum += __shfl_xor(sum, off);
        float inv = 1.f / sum;
#pragma unroll
        for (int l = 0; l < 8; ++l) e[l] *= inv;
        float* arow = attn + (bh * NN + i0 + row) * NN + lane * 8;
        float4 o0; o0.x = e[0]; o0.y = e[1]; o0.z = e[2]; o0.w = e[3];
        float4 o1; o1.x = e[4]; o1.y = e[5]; o1.z = e[6]; o1.w = e[7];
        *(float4*)(arow) = o0;
        *(float4*)(arow + 4) = o1;
        uint4 pk;
        pk.x = cvt_pk_bf16(e[0], e[1]); pk.y = cvt_pk_bf16(e[2], e[3]);
        pk.z = cvt_pk_bf16(e[4], e[5]); pk.w = cvt_pk_bf16(e[6], e[7]);
        *(uint4*)((char*)s_ab + row * 1040 + lane * 16) = pk;
    }
    __syncthreads();

    // ---- attn @ V: wave w = (part = w>>1 [V hi/lo], nh = w&1 [d half]) ----
    {
        int part = w >> 1, nh = w & 1;
        const float* vbase = vT + (bh * HDIM + nh * 16 + r) * NN;
        f32x4 acc = {0.f, 0.f, 0.f, 0.f};
        for (int kt = 0; kt < 16; ++kt) {
            bf16x8 af = *(bf16x8*)((char*)s_ab + r * 1040 + kt * 64 + q2 * 16);
            const float4* vp = (const float4*)(vbase + kt * 32 + q2 * 8);
            float4 x0 = vp[0], x1 = vp[1];
            float xs[8] = {x0.x, x0.y, x0.z, x0.w, x1.x, x1.y, x1.z, x1.w};
            bf16x8 bfg;
            if (part == 0) {
                unsigned hu[4];
#pragma unroll
                for (int p = 0; p < 4; ++p) {
                    unsigned a0 = __float_as_uint(xs[2*p]), a1 = __float_as_uint(xs[2*p+1]);
                    hu[p] = (a0 >> 16) | (a1 & 0xFFFF0000u);
                }
                int4 hv; hv.x = hu[0]; hv.y = hu[1]; hv.z = hu[2]; hv.w = hu[3];
                bfg = *(bf16x8*)&hv;
            } else {
                unsigned lu[4];
#pragma unroll
                for (int p = 0; p < 4; ++p) {
                    unsigned a0 = __float_as_uint(xs[2*p]), a1 = __float_as_uint(xs[2*p+1]);
                    float h0 = __uint_as_float(a0 & 0xFFFF0000u);
                    float h1 = __uint_as_float(a1 & 0xFFFF0000u);
                    lu[p] = cvt_pk_bf16(xs[2*p] - h0, xs[2*p+1] - h1);
                }
                int4 lv; lv.x = lu[0]; lv.y = lu[1]; lv.z = lu[2]; lv.w = lu[3];
                bfg = *(bf16x8*)&lv;
            }
            acc = __builtin_amdgcn_mfma_f32_16x16x32_bf16(af, bfg, acc, 0, 0, 0);
        }
#pragma unroll
        for (int reg = 0; reg < 4; ++reg)
            s_out[part][q2 * 4 + reg][nh * 16 + r] = acc[reg];
    }
    __syncthreads();

    // ---- ao write: channel = h*32+d ----
#pragma unroll
    for (int rep = 0; rep < 2; ++rep) {
        int idx = rep * 256 + t;
        int row = idx >> 5, d = idx & 31;
        ao[((size_t)b * NN + i0 + row) * HID + h * HDIM + d] =
            s_out[0][row][d] + s_out[1][row][d];
    }
}

// ---------- kernel 4: Wo + residual + LayerNorm + relu, 4 rows/block ----------
__global__ __launch_bounds__(256) void k_final(
    const float* __restrict__ ao, const float* __restrict__ node_h,
    const float* __restrict__ Wo, const float* __restrict__ bo,
    const float* __restrict__ ln_g, const float* __restrict__ ln_b,
    float* __restrict__ out) {
    int blk = blockIdx.x;           // 512 blocks
    size_t bi0 = (size_t)blk * 4;
    int t = threadIdx.x;
    __shared__ __align__(16) float s_a[4][HID];
    __shared__ float s_red[4][4][2];
#pragma unroll
    for (int u = 0; u < 4; ++u)
        s_a[u][t] = ao[(bi0 + u) * HID + t];
    __syncthreads();
    float bov = bo[t];
    float o[4];
#pragma unroll
    for (int u = 0; u < 4; ++u) o[u] = bov;
#pragma unroll 4
    for (int rr = 0; rr < HID; ++rr) {
        float wo = Wo[rr * HID + t];
#pragma unroll
        for (int u = 0; u < 4; ++u) o[u] = fmaf(s_a[u][rr], wo, o[u]);
    }
    float g = ln_g[t], bb = ln_b[t];
    int wave = t >> 6, ln = t & 63;
    float x[4];
#pragma unroll
    for (int u = 0; u < 4; ++u) {
        x[u] = node_h[(bi0 + u) * HID + t] + o[u];
        float s1 = x[u], s2 = x[u] * x[u];
#pragma unroll
        for (int off = 32; off > 0; off >>= 1) { s1 += __shfl_xor(s1, off); s2 += __shfl_xor(s2, off); }
        if (ln == 0) { s_red[u][wave][0] = s1; s_red[u][wave][1] = s2; }
    }
    __syncthreads();
#pragma unroll
    for (int u = 0; u < 4; ++u) {
        float s1 = s_red[u][0][0] + s_red[u][1][0] + s_red[u][2][0] + s_red[u][3][0];
        float s2 = s_red[u][0][1] + s_red[u][1][1] + s_red[u][2][1] + s_red[u][3][1];
        float mean = s1 * (1.f / HID);
        float var = s2 * (1.f / HID) - mean * mean;
        float inv = rsqrtf(var + 1e-5f);
        float y = (x[u] - mean) * inv * g + bb;
        out[(bi0 + u) * HID + t] = fmaxf(y, 0.f);
    }
}

extern "C" void kernel_launch(void* const* d_in, const int* in_sizes, int n_in,
                              void* d_out, int out_size, void* d_ws, size_t ws_size,
                              hipStream_t stream) {
    const float* node_h = (const float*)d_in[0];
    const float* edge_x = (const float*)d_in[1];
    const int*   emask  = (const int*)d_in[2];
    const float* Wq = (const float*)d_in[3];
    const float* bq = (const float*)d_in[4];
    const float* Wk = (const float*)d_in[5];
    const float* bk = (const float*)d_in[6];
    const float* Wv = (const float*)d_in[7];
    const float* bv = (const float*)d_in[8];
    const float* We1 = (const float*)d_in[9];
    const float* be1 = (const float*)d_in[10];
    const float* We2 = (const float*)d_in[11];
    const float* be2 = (const float*)d_in[12];
    const float* Wo = (const float*)d_in[13];
    const float* bo = (const float*)d_in[14];
    const float* ln_g = (const float*)d_in[15];
    const float* ln_b = (const float*)d_in[16];

    float* out_x  = (float*)d_out;                              // [4,512,256]
    float* out_at = (float*)d_out + (size_t)BATCH * NN * HID;   // [4,8,512,512] (eb then attn)

    float* ws = (float*)d_ws;
    float* q    = ws;                                  // 524288 floats
    float* kbuf = ws + 524288;
    float* vT   = ws + 1048576;
    float* ao   = ws + 1572864;
    unsigned short* W1P = (unsigned short*)(ws + 2097152);  // 8192 ushorts
    unsigned short* W2P = W1P + 8192;                       // 4096 ushorts

    const int NBI = BATCH * NN;  // 2048

    hipLaunchKernelGGL(k_pack, dim3(1), dim3(256), 0, stream, We1, be1, We2, W1P, W2P);
    hipLaunchKernelGGL(k_qkv, dim3(NBI / 4), dim3(256), 0, stream,
                       node_h, Wq, bq, Wk, bk, Wv, bv, q, kbuf, vT);
    hipLaunchKernelGGL(k_eb, dim3(1024), dim3(256), 0, stream,
                       edge_x, W1P, W2P, be2, out_at);
    hipLaunchKernelGGL(k_attn2, dim3(1024), dim3(256), 0, stream,
                       emask, q, kbuf, vT, out_at, ao);
    hipLaunchKernelGGL(k_final, dim3(NBI / 4), dim3(256), 0, stream,
                       ao, node_h, Wo, bo, ln_g, ln_b, out_x);
}